// Round 5
// baseline (430.895 us; speedup 1.0000x reference)
//
#include <hip/hip_runtime.h>

#define N_IMG 100000
#define C_CLS 1000
#define CP    1024    // padded class count
#define DIM   512     // att_dim == img_dim
#define HPROJ 256     // H
#define CAP   512     // per-class bucket capacity

// ---------------------------------------------------------------------------
// One shared-memory union for all 512-thread kernels (max = score: 38.3 KB)
// ---------------------------------------------------------------------------
union BSm {
    struct { float At[64][33]; float Wt[64][36]; float nps[32][17]; } p;  // proj1/projB
    struct { float Xi[64][68]; float Xj[64][68]; float rp[64][17]; } s;   // score
    struct { float Wt[64][36]; float Bt[64][68]; float nps[32][17]; } q;  // mmqt
    struct { float Wt[64][36]; float Vt[64][68]; } m2;                    // mm_out
    struct { int list[CAP]; float4 acc[3][128]; } g;                      // gather
};

// ---------------------------------------------------------------------------
// proj1: PT[j][i] = (A @ Wm)^T, full-K (512), fused squared-norm partials
// atomicAdd'ed into nsum[i]. 256 blocks (8j x 32i), tile 32i x 32j, 512 thr.
// ---------------------------------------------------------------------------
__device__ __forceinline__ void proj1_dev(BSm& sm, int b, int t,
    const float* __restrict__ A0, const float* __restrict__ Wm,
    float* __restrict__ PT, float* __restrict__ nsum)
{
    const int j0 = (b & 7) * 32;
    const int i0 = (b >> 3) * 32;
    const int ti = t & 31;      // i lane
    const int tj = t >> 5;      // j-pair 0..15
    float acc0 = 0.f, acc1 = 0.f;
    for (int ch = 0; ch < 8; ++ch) {
        const int kb = ch * 64;
        __syncthreads();
        {   // A-tile (32 i x 64 k) k-major: one float4 per thread
            const int r = t >> 4, f = t & 15;
            const int row = min(i0 + r, C_CLS - 1);
            const float4 v = *(const float4*)(A0 + (size_t)row * DIM + kb + 4 * f);
            sm.p.At[4*f+0][r] = v.x; sm.p.At[4*f+1][r] = v.y;
            sm.p.At[4*f+2][r] = v.z; sm.p.At[4*f+3][r] = v.w;
        }
        {   // W-tile (64 k x 32 j): one float4 per thread
            const int kk = t >> 3, f = t & 7;
            *(float4*)&sm.p.Wt[kk][4*f] =
                *(const float4*)(Wm + (size_t)(kb + kk) * HPROJ + j0 + 4 * f);
        }
        __syncthreads();
#pragma unroll 8
        for (int kk = 0; kk < 64; ++kk) {
            const float  a = sm.p.At[kk][ti];
            const float2 w = *(const float2*)&sm.p.Wt[kk][2 * tj];
            acc0 = fmaf(a, w.x, acc0);
            acc1 = fmaf(a, w.y, acc1);
        }
    }
    const int i = i0 + ti, j = j0 + 2 * tj;
    PT[(size_t)j       * CP + i] = acc0;
    PT[(size_t)(j + 1) * CP + i] = acc1;
    sm.p.nps[ti][tj] = acc0 * acc0 + acc1 * acc1;
    __syncthreads();
    if (t < 32) {
        float s = 0.f;
#pragma unroll
        for (int k = 0; k < 16; ++k) s += sm.p.nps[t][k];
        atomicAdd(&nsum[i0 + t], s);
    }
}

// ---------------------------------------------------------------------------
// projB: B[i][h] = (A @ Wm)[i][h], natural layout, no norms.
// 256 blocks (8h x 32i), tile 32i x 32h, 512 threads.
// ---------------------------------------------------------------------------
__device__ __forceinline__ void projB_dev(BSm& sm, int b, int t,
    const float* __restrict__ A0, const float* __restrict__ Wm,
    float* __restrict__ B)
{
    const int j0 = (b & 7) * 32;    // h
    const int i0 = (b >> 3) * 32;   // row
    const int tc = t & 15;          // h-pair 0..15
    const int tr = t >> 4;          // row 0..31
    float acc0 = 0.f, acc1 = 0.f;
    for (int ch = 0; ch < 8; ++ch) {
        const int kb = ch * 64;
        __syncthreads();
        {
            const int r = t >> 4, f = t & 15;
            const int row = min(i0 + r, C_CLS - 1);
            const float4 v = *(const float4*)(A0 + (size_t)row * DIM + kb + 4 * f);
            sm.p.At[4*f+0][r] = v.x; sm.p.At[4*f+1][r] = v.y;
            sm.p.At[4*f+2][r] = v.z; sm.p.At[4*f+3][r] = v.w;
        }
        {
            const int kk = t >> 3, f = t & 7;
            *(float4*)&sm.p.Wt[kk][4*f] =
                *(const float4*)(Wm + (size_t)(kb + kk) * HPROJ + j0 + 4 * f);
        }
        __syncthreads();
#pragma unroll 8
        for (int kk = 0; kk < 64; ++kk) {
            const float  a = sm.p.At[kk][tr];
            const float2 w = *(const float2*)&sm.p.Wt[kk][2 * tc];
            acc0 = fmaf(a, w.x, acc0);
            acc1 = fmaf(a, w.y, acc1);
        }
    }
    // B sized [1024][256]; pad rows hold dup of row 999 (multiplied by W=0 later)
    *(float2*)(B + (size_t)(i0 + tr) * HPROJ + j0 + 2 * tc) = make_float2(acc0, acc1);
}

// ---------------------------------------------------------------------------
// gather: per-class mean of image_feats rows -> protos[c]. 512 threads.
// ---------------------------------------------------------------------------
__device__ __forceinline__ void gather_dev(BSm& sm, int c, int t,
    const float* __restrict__ image_feats, const int* __restrict__ cnt,
    const int* __restrict__ perm, float* __restrict__ protos)
{
    const int n = min(cnt[c], CAP);
    for (int m = t; m < n; m += 512) sm.g.list[m] = perm[c * CAP + m];
    __syncthreads();
    const int q  = t >> 7;     // row-stream quarter 0..3
    const int tc = t & 127;    // float4 column group
    float4 a0 = {0,0,0,0}, a1 = {0,0,0,0};
    int m = q;
    for (; m + 4 < n; m += 8) {
        const float4 v0 = *(const float4*)(image_feats + (size_t)sm.g.list[m]     * DIM + 4 * tc);
        const float4 v1 = *(const float4*)(image_feats + (size_t)sm.g.list[m + 4] * DIM + 4 * tc);
        a0.x += v0.x; a0.y += v0.y; a0.z += v0.z; a0.w += v0.w;
        a1.x += v1.x; a1.y += v1.y; a1.z += v1.z; a1.w += v1.w;
    }
    for (; m < n; m += 4) {
        const float4 v0 = *(const float4*)(image_feats + (size_t)sm.g.list[m] * DIM + 4 * tc);
        a0.x += v0.x; a0.y += v0.y; a0.z += v0.z; a0.w += v0.w;
    }
    a0.x += a1.x; a0.y += a1.y; a0.z += a1.z; a0.w += a1.w;
    if (q) sm.g.acc[q - 1][tc] = a0;
    __syncthreads();
    if (q == 0) {
        const float4 o1 = sm.g.acc[0][tc];
        const float4 o2 = sm.g.acc[1][tc];
        const float4 o3 = sm.g.acc[2][tc];
        const float inv = 1.0f / (float)n;
        float4 r;
        r.x = (a0.x + o1.x + o2.x + o3.x) * inv;
        r.y = (a0.y + o1.y + o2.y + o3.y) * inv;
        r.z = (a0.z + o1.z + o2.z + o3.z) * inv;
        r.w = (a0.w + o1.w + o2.w + o3.w) * inv;
        *(float4*)(protos + (size_t)c * DIM + 4 * tc) = r;
    }
}

// ---------------------------------------------------------------------------
// score: WT[j][i] = maskexp(dot_ij * rsqrt(nsum_i) * rsqrt(nsum_j)); fused
// row-sum atomics. 256 blocks (16j x 16i), 64x64 tile, 2i x 4j per thread.
// ---------------------------------------------------------------------------
__device__ __forceinline__ void score_dev(BSm& sm, int b, int t,
    const float* __restrict__ PT, const float* __restrict__ nsum,
    float* __restrict__ WT, float* __restrict__ rsum)
{
    const int j0 = (b & 15) * 64;
    const int i0 = (b >> 4) * 64;
    const int tx = t & 15, ty = t >> 4;   // ty 0..31
    float acc[2][4] = {};
    for (int ch = 0; ch < 4; ++ch) {
        const int kb = ch * 64;
        __syncthreads();
        for (int l = t; l < 1024; l += 512) {
            const int kk = l >> 4, f = l & 15;
            const float* src = PT + (size_t)(kb + kk) * CP;
            *(float4*)&sm.s.Xi[kk][4 * f] = *(const float4*)(src + i0 + 4 * f);
            *(float4*)&sm.s.Xj[kk][4 * f] = *(const float4*)(src + j0 + 4 * f);
        }
        __syncthreads();
#pragma unroll 8
        for (int kk = 0; kk < 64; ++kk) {
            const float2 a  = *(const float2*)&sm.s.Xi[kk][2 * ty];
            const float4 bb = *(const float4*)&sm.s.Xj[kk][4 * tx];
            const float av[2] = {a.x, a.y};
            const float bv[4] = {bb.x, bb.y, bb.z, bb.w};
#pragma unroll
            for (int u = 0; u < 2; ++u)
#pragma unroll
                for (int v = 0; v < 4; ++v)
                    acc[u][v] = fmaf(av[u], bv[v], acc[u][v]);
        }
    }
    const float rni0 = rsqrtf(nsum[i0 + 2 * ty + 0]);
    const float rni1 = rsqrtf(nsum[i0 + 2 * ty + 1]);
    float rp0 = 0.f, rp1 = 0.f;
#pragma unroll
    for (int v = 0; v < 4; ++v) {
        const int j = j0 + 4 * tx + v;
        const bool jv = (j < C_CLS);
        const float rnj = rsqrtf(nsum[j]);
        const float d0 = acc[0][v] * rni0 * rnj;
        const float d1 = acc[1][v] * rni1 * rnj;
        const float w0 = (jv && d0 > 0.5f) ? __expf(10.f * d0) : 0.f;
        const float w1 = (jv && d1 > 0.5f) ? __expf(10.f * d1) : 0.f;
        rp0 += w0; rp1 += w1;
        *(float2*)(WT + (size_t)j * CP + i0 + 2 * ty) = make_float2(w0, w1);
    }
    sm.s.rp[2 * ty + 0][tx] = rp0;
    sm.s.rp[2 * ty + 1][tx] = rp1;
    __syncthreads();
    if (t < 64) {
        float s = 0.f;
#pragma unroll 16
        for (int k = 0; k < 16; ++k) s += sm.s.rp[t][k];
        const int i = i0 + t;
        if (i < C_CLS) atomicAdd(&rsum[i], s);
    }
}

// ---------------------------------------------------------------------------
// mmqt: QT[h][i] = (W @ B)^T, full-K (1024), fused nsum atomics.
// 128 blocks (4h x 32i), tile 32i x 64h, 1i x 4h per thread, 512 threads.
// WT rows j>=1000 are zeros, so B pad rows contribute nothing.
// ---------------------------------------------------------------------------
__device__ __forceinline__ void mmqt_dev(BSm& sm, int b, int t,
    const float* __restrict__ WT, const float* __restrict__ B,
    float* __restrict__ QT, float* __restrict__ nsum)
{
    const int h0 = (b & 3) * 64;
    const int i0 = (b >> 2) * 32;
    const int ti = t & 31;      // i lane
    const int th = t >> 5;      // 0..15, 4h each
    float acc[4] = {};
    for (int ch = 0; ch < 16; ++ch) {
        const int kb = ch * 64;
        __syncthreads();
        {   // W-tile (64 k x 32 i): one float4 per thread
            const int kk = t >> 3, f = t & 7;
            *(float4*)&sm.q.Wt[kk][4 * f] =
                *(const float4*)(WT + (size_t)(kb + kk) * CP + i0 + 4 * f);
        }
        for (int l = t; l < 1024; l += 512) {   // B-tile (64 k x 64 h)
            const int kk = l >> 4, f = l & 15;
            *(float4*)&sm.q.Bt[kk][4 * f] =
                *(const float4*)(B + (size_t)(kb + kk) * HPROJ + h0 + 4 * f);
        }
        __syncthreads();
#pragma unroll 8
        for (int kk = 0; kk < 64; ++kk) {
            const float  w = sm.q.Wt[kk][ti];
            const float4 v = *(const float4*)&sm.q.Bt[kk][4 * th];
            acc[0] = fmaf(w, v.x, acc[0]);
            acc[1] = fmaf(w, v.y, acc[1]);
            acc[2] = fmaf(w, v.z, acc[2]);
            acc[3] = fmaf(w, v.w, acc[3]);
        }
    }
    const int i = i0 + ti;
#pragma unroll
    for (int u = 0; u < 4; ++u)
        QT[(size_t)(h0 + 4 * th + u) * CP + i] = acc[u];
    sm.q.nps[ti][th] = acc[0]*acc[0] + acc[1]*acc[1] + acc[2]*acc[2] + acc[3]*acc[3];
    __syncthreads();
    if (t < 32) {
        float s = 0.f;
#pragma unroll
        for (int k = 0; k < 16; ++k) s += sm.q.nps[t][k];
        atomicAdd(&nsum[i0 + t], s);
    }
}

// ---------------------------------------------------------------------------
// mm_out (full-K, 256 blocks): out[i] = (W @ V)[i] / rsum[i], V via vidx.
// grid (8c x 32i), tile 32i x 64c, K=1024 in 16 chunks, 1i x 4c per thread.
// ---------------------------------------------------------------------------
__device__ __forceinline__ void mm_out_dev(BSm& sm, int b, int t,
    const float* __restrict__ WT, const float* __restrict__ V,
    const int* __restrict__ vidx, const float* __restrict__ rsum,
    float* __restrict__ Out)
{
    const int c0 = (b & 7) * 64;
    const int i0 = (b >> 3) * 32;
    const int tx = t & 15, ty = t >> 4;   // ty 0..31 = i
    float acc[4] = {};
    for (int ch = 0; ch < 16; ++ch) {
        const int kb = ch * 64;
        __syncthreads();
        {
            const int kk = t >> 3, f = t & 7;
            *(float4*)&sm.m2.Wt[kk][4 * f] =
                *(const float4*)(WT + (size_t)(kb + kk) * CP + i0 + 4 * f);
        }
        for (int l = t; l < 1024; l += 512) {
            const int kk = l >> 4, f = l & 15;
            const int jc = min(kb + kk, C_CLS - 1);
            const int vr = vidx[jc];
            *(float4*)&sm.m2.Vt[kk][4 * f] =
                *(const float4*)(V + (size_t)vr * DIM + c0 + 4 * f);
        }
        __syncthreads();
#pragma unroll 8
        for (int kk = 0; kk < 64; ++kk) {
            const float  w = sm.m2.Wt[kk][ty];
            const float4 v = *(const float4*)&sm.m2.Vt[kk][4 * tx];
            acc[0] = fmaf(w, v.x, acc[0]);
            acc[1] = fmaf(w, v.y, acc[1]);
            acc[2] = fmaf(w, v.z, acc[2]);
            acc[3] = fmaf(w, v.w, acc[3]);
        }
    }
    const int i = i0 + ty;
    if (i < C_CLS) {
        const float s = 1.0f / rsum[i];
        float4 o = {acc[0] * s, acc[1] * s, acc[2] * s, acc[3] * s};
        *(float4*)(Out + (size_t)i * DIM + c0 + 4 * tx) = o;
    }
}

// ---------------------------------------------------------------------------
// Kernels
// ---------------------------------------------------------------------------
__global__ __launch_bounds__(512) void k_stage1(
    const float* __restrict__ attributes,
    const float* __restrict__ att_h, const float* __restrict__ att_g,
    float* __restrict__ PT, float* __restrict__ nsum1, float* __restrict__ B,
    const int* __restrict__ labels, int* __restrict__ cnt,
    int* __restrict__ perm)
{
    __shared__ BSm sm;
    const int b = blockIdx.x, t = threadIdx.x;
    if (b < 256) {
        proj1_dev(sm, b, t, attributes, att_h, PT, nsum1);
    } else if (b < 512) {
        projB_dev(sm, b - 256, t, attributes, att_g, B);
    } else {
        const int i = (b - 512) * 512 + t;
        if (i < N_IMG) {
            const int c = labels[i];
            const int p = atomicAdd(&cnt[c], 1);
            if (p < CAP) perm[c * CAP + p] = i;
        }
    }
}

__global__ __launch_bounds__(512) void k_score_gather(
    const float* __restrict__ PT, const float* __restrict__ nsum,
    float* __restrict__ WT, float* __restrict__ rsum,
    const float* __restrict__ image_feats, const int* __restrict__ cnt,
    const int* __restrict__ perm, float* __restrict__ protos, int cbase)
{
    __shared__ BSm sm;
    const int b = blockIdx.x, t = threadIdx.x;
    if (b < 256) score_dev(sm, b, t, PT, nsum, WT, rsum);
    else         gather_dev(sm, cbase + (b - 256), t, image_feats, cnt, perm, protos);
}

__global__ __launch_bounds__(512) void k_mmqt_gather(
    const float* __restrict__ WT, const float* __restrict__ B,
    float* __restrict__ QT, float* __restrict__ nsum,
    const float* __restrict__ image_feats, const int* __restrict__ cnt,
    const int* __restrict__ perm, float* __restrict__ protos, int cbase)
{
    __shared__ BSm sm;
    const int b = blockIdx.x, t = threadIdx.x;
    if (b < 128) mmqt_dev(sm, b, t, WT, B, QT, nsum);
    else         gather_dev(sm, cbase + (b - 128), t, image_feats, cnt, perm, protos);
}

__global__ __launch_bounds__(512) void k_mm_out(
    const float* __restrict__ WT, const float* __restrict__ V,
    const int* __restrict__ vidx, const float* __restrict__ rsum,
    float* __restrict__ Out)
{
    __shared__ BSm sm;
    mm_out_dev(sm, blockIdx.x, threadIdx.x, WT, V, vidx, rsum, Out);
}

// ---------------------------------------------------------------------------
extern "C" void kernel_launch(void* const* d_in, const int* in_sizes, int n_in,
                              void* d_out, int out_size, void* d_ws, size_t ws_size,
                              hipStream_t stream) {
    const float* image_feats = (const float*)d_in[0];  // [100000, 512]
    const float* attributes  = (const float*)d_in[1];  // [1000, 512]
    const float* att_g       = (const float*)d_in[2];  // [512, 256]
    const float* att_h       = (const float*)d_in[3];  // [512, 256]
    const int*   labels      = (const int*)d_in[4];    // [100000]
    const int*   tpl         = (const int*)d_in[5];    // [1000]
    float* out = (float*)d_out;                        // [1000, 512]

    float* ws     = (float*)d_ws;
    float* protos = ws;                       // 512000
    float* PT1    = protos + 512000;          // 262144  [256][1024]
    float* PT2    = PT1 + 262144;             // 262144  [256][1024]
    float* WT     = PT2 + 262144;             // 1048576 [1024][1024]
    float* B      = WT + 1048576;             // 262144  [1024][256]
    int*   cnt    = (int*)(B + 262144);       // 1024  (zero-block start)
    float* rsum1  = (float*)(cnt + 1024);     // 1024 (unused downstream)
    float* rsum2  = rsum1 + 1024;             // 1024
    float* nsum1  = rsum2 + 1024;             // 1024
    float* nsum2  = nsum1 + 1024;             // 1024
    int*   perm   = (int*)(nsum2 + 1024);     // 512000

    hipMemsetAsync(cnt, 0, 5 * 1024 * sizeof(int), stream);

    // K1: proj1 (attr@att_h -> PT1, nsum1) ∥ projB (attr@att_g -> B) ∥ fill
    k_stage1<<<512 + 196, 512, 0, stream>>>(
        attributes, att_h, att_g, PT1, nsum1, B, labels, cnt, perm);
    // K2: score1 ∥ gather [0,334)   (rsum1 written but never read: scale
    //     cancels in cosine normalization of stage 2)
    k_score_gather<<<256 + 334, 512, 0, stream>>>(
        PT1, nsum1, WT, rsum1, image_feats, cnt, perm, protos, 0);
    // K3: mmqt (W1@B -> PT2 transposed, nsum2) ∥ gather [334,667)
    k_mmqt_gather<<<128 + 333, 512, 0, stream>>>(
        WT, B, PT2, nsum2, image_feats, cnt, perm, protos, 334);
    // K4: score2 ∥ gather [667,1000)
    k_score_gather<<<256 + 333, 512, 0, stream>>>(
        PT2, nsum2, WT, rsum2, image_feats, cnt, perm, protos, 667);
    // K5: mm_out full-K, fused 1/rsum2 scale, writes out directly
    k_mm_out<<<256, 512, 0, stream>>>(WT, protos, tpl, rsum2, out);
}

// Round 6
// 429.305 us; speedup vs baseline: 1.0037x; 1.0037x over previous
//
#include <hip/hip_runtime.h>

#define N_IMG 100000
#define C_CLS 1000
#define CP    1024    // padded class count
#define DIM   512     // att_dim == img_dim
#define HPROJ 256     // H
#define CAP   512     // per-class bucket capacity

// ---------------------------------------------------------------------------
// One shared-memory union for all 512-thread kernels (max = score: 39.2 KB)
// ---------------------------------------------------------------------------
union BSm {
    struct { float At[64][33]; float Wt[64][36]; float nps[32][17]; } p;  // proj1/projB
    struct { float Xi[64][68]; float Xj[64][68]; float rp[64][17]; } s;   // score
    struct { float Wt[128][36]; float Bt[128][36]; float nps[32][17]; } q;// mmqt v2
    struct { float Wt[64][36]; float Vt[64][68]; } m2;                    // mm_out
    struct { int list[CAP]; float4 acc[3][128]; } g;                      // gather
};

// ---------------------------------------------------------------------------
// proj1: PT[j][i] = (A @ Wm)^T, full-K (512), fused squared-norm partials
// atomicAdd'ed into nsum[i]. 256 blocks (8j x 32i), tile 32i x 32j, 512 thr.
// ---------------------------------------------------------------------------
__device__ __forceinline__ void proj1_dev(BSm& sm, int b, int t,
    const float* __restrict__ A0, const float* __restrict__ Wm,
    float* __restrict__ PT, float* __restrict__ nsum)
{
    const int j0 = (b & 7) * 32;
    const int i0 = (b >> 3) * 32;
    const int ti = t & 31;      // i lane
    const int tj = t >> 5;      // j-pair 0..15
    float acc0 = 0.f, acc1 = 0.f;
    for (int ch = 0; ch < 8; ++ch) {
        const int kb = ch * 64;
        __syncthreads();
        {   // A-tile (32 i x 64 k) k-major: one float4 per thread
            const int r = t >> 4, f = t & 15;
            const int row = min(i0 + r, C_CLS - 1);
            const float4 v = *(const float4*)(A0 + (size_t)row * DIM + kb + 4 * f);
            sm.p.At[4*f+0][r] = v.x; sm.p.At[4*f+1][r] = v.y;
            sm.p.At[4*f+2][r] = v.z; sm.p.At[4*f+3][r] = v.w;
        }
        {   // W-tile (64 k x 32 j): one float4 per thread
            const int kk = t >> 3, f = t & 7;
            *(float4*)&sm.p.Wt[kk][4*f] =
                *(const float4*)(Wm + (size_t)(kb + kk) * HPROJ + j0 + 4 * f);
        }
        __syncthreads();
#pragma unroll 8
        for (int kk = 0; kk < 64; ++kk) {
            const float  a = sm.p.At[kk][ti];
            const float2 w = *(const float2*)&sm.p.Wt[kk][2 * tj];
            acc0 = fmaf(a, w.x, acc0);
            acc1 = fmaf(a, w.y, acc1);
        }
    }
    const int i = i0 + ti, j = j0 + 2 * tj;
    PT[(size_t)j       * CP + i] = acc0;
    PT[(size_t)(j + 1) * CP + i] = acc1;
    sm.p.nps[ti][tj] = acc0 * acc0 + acc1 * acc1;
    __syncthreads();
    if (t < 32) {
        float s = 0.f;
#pragma unroll
        for (int k = 0; k < 16; ++k) s += sm.p.nps[t][k];
        atomicAdd(&nsum[i0 + t], s);
    }
}

// ---------------------------------------------------------------------------
// projB: B[i][h] = (A @ Wm)[i][h], natural layout, no norms.
// 256 blocks (8h x 32i), tile 32i x 32h, 512 threads.
// ---------------------------------------------------------------------------
__device__ __forceinline__ void projB_dev(BSm& sm, int b, int t,
    const float* __restrict__ A0, const float* __restrict__ Wm,
    float* __restrict__ B)
{
    const int j0 = (b & 7) * 32;    // h
    const int i0 = (b >> 3) * 32;   // row
    const int tc = t & 15;          // h-pair 0..15
    const int tr = t >> 4;          // row 0..31
    float acc0 = 0.f, acc1 = 0.f;
    for (int ch = 0; ch < 8; ++ch) {
        const int kb = ch * 64;
        __syncthreads();
        {
            const int r = t >> 4, f = t & 15;
            const int row = min(i0 + r, C_CLS - 1);
            const float4 v = *(const float4*)(A0 + (size_t)row * DIM + kb + 4 * f);
            sm.p.At[4*f+0][r] = v.x; sm.p.At[4*f+1][r] = v.y;
            sm.p.At[4*f+2][r] = v.z; sm.p.At[4*f+3][r] = v.w;
        }
        {
            const int kk = t >> 3, f = t & 7;
            *(float4*)&sm.p.Wt[kk][4*f] =
                *(const float4*)(Wm + (size_t)(kb + kk) * HPROJ + j0 + 4 * f);
        }
        __syncthreads();
#pragma unroll 8
        for (int kk = 0; kk < 64; ++kk) {
            const float  a = sm.p.At[kk][tr];
            const float2 w = *(const float2*)&sm.p.Wt[kk][2 * tc];
            acc0 = fmaf(a, w.x, acc0);
            acc1 = fmaf(a, w.y, acc1);
        }
    }
    // B sized [1024][256]; pad rows hold dup of row 999 (multiplied by W=0 later)
    *(float2*)(B + (size_t)(i0 + tr) * HPROJ + j0 + 2 * tc) = make_float2(acc0, acc1);
}

// ---------------------------------------------------------------------------
// gather: per-class mean of image_feats rows -> protos[c]. 512 threads.
// 4 row-streams x 4 outstanding loads per thread.
// ---------------------------------------------------------------------------
__device__ __forceinline__ void gather_dev(BSm& sm, int c, int t,
    const float* __restrict__ image_feats, const int* __restrict__ cnt,
    const int* __restrict__ perm, float* __restrict__ protos)
{
    const int n = min(cnt[c], CAP);
    for (int m = t; m < n; m += 512) sm.g.list[m] = perm[c * CAP + m];
    __syncthreads();
    const int q  = t >> 7;     // row-stream quarter 0..3
    const int tc = t & 127;    // float4 column group
    float4 a0 = {0,0,0,0}, a1 = {0,0,0,0};
    int m = q;
    for (; m + 12 < n; m += 16) {
        const float4 v0 = *(const float4*)(image_feats + (size_t)sm.g.list[m]      * DIM + 4 * tc);
        const float4 v1 = *(const float4*)(image_feats + (size_t)sm.g.list[m + 4]  * DIM + 4 * tc);
        const float4 v2 = *(const float4*)(image_feats + (size_t)sm.g.list[m + 8]  * DIM + 4 * tc);
        const float4 v3 = *(const float4*)(image_feats + (size_t)sm.g.list[m + 12] * DIM + 4 * tc);
        a0.x += v0.x; a0.y += v0.y; a0.z += v0.z; a0.w += v0.w;
        a1.x += v1.x; a1.y += v1.y; a1.z += v1.z; a1.w += v1.w;
        a0.x += v2.x; a0.y += v2.y; a0.z += v2.z; a0.w += v2.w;
        a1.x += v3.x; a1.y += v3.y; a1.z += v3.z; a1.w += v3.w;
    }
    for (; m < n; m += 4) {
        const float4 v0 = *(const float4*)(image_feats + (size_t)sm.g.list[m] * DIM + 4 * tc);
        a0.x += v0.x; a0.y += v0.y; a0.z += v0.z; a0.w += v0.w;
    }
    a0.x += a1.x; a0.y += a1.y; a0.z += a1.z; a0.w += a1.w;
    if (q) sm.g.acc[q - 1][tc] = a0;
    __syncthreads();
    if (q == 0) {
        const float4 o1 = sm.g.acc[0][tc];
        const float4 o2 = sm.g.acc[1][tc];
        const float4 o3 = sm.g.acc[2][tc];
        const float inv = 1.0f / (float)n;
        float4 r;
        r.x = (a0.x + o1.x + o2.x + o3.x) * inv;
        r.y = (a0.y + o1.y + o2.y + o3.y) * inv;
        r.z = (a0.z + o1.z + o2.z + o3.z) * inv;
        r.w = (a0.w + o1.w + o2.w + o3.w) * inv;
        *(float4*)(protos + (size_t)c * DIM + 4 * tc) = r;
    }
}

// ---------------------------------------------------------------------------
// score: WT[j][i] = maskexp(dot_ij * rsqrt(nsum_i) * rsqrt(nsum_j)); fused
// row-sum atomics. 256 blocks (16j x 16i), 64x64 tile, 2i x 4j per thread.
// ---------------------------------------------------------------------------
__device__ __forceinline__ void score_dev(BSm& sm, int b, int t,
    const float* __restrict__ PT, const float* __restrict__ nsum,
    float* __restrict__ WT, float* __restrict__ rsum)
{
    const int j0 = (b & 15) * 64;
    const int i0 = (b >> 4) * 64;
    const int tx = t & 15, ty = t >> 4;   // ty 0..31
    float acc[2][4] = {};
    for (int ch = 0; ch < 4; ++ch) {
        const int kb = ch * 64;
        __syncthreads();
        for (int l = t; l < 1024; l += 512) {
            const int kk = l >> 4, f = l & 15;
            const float* src = PT + (size_t)(kb + kk) * CP;
            *(float4*)&sm.s.Xi[kk][4 * f] = *(const float4*)(src + i0 + 4 * f);
            *(float4*)&sm.s.Xj[kk][4 * f] = *(const float4*)(src + j0 + 4 * f);
        }
        __syncthreads();
#pragma unroll 8
        for (int kk = 0; kk < 64; ++kk) {
            const float2 a  = *(const float2*)&sm.s.Xi[kk][2 * ty];
            const float4 bb = *(const float4*)&sm.s.Xj[kk][4 * tx];
            const float av[2] = {a.x, a.y};
            const float bv[4] = {bb.x, bb.y, bb.z, bb.w};
#pragma unroll
            for (int u = 0; u < 2; ++u)
#pragma unroll
                for (int v = 0; v < 4; ++v)
                    acc[u][v] = fmaf(av[u], bv[v], acc[u][v]);
        }
    }
    const float rni0 = rsqrtf(nsum[i0 + 2 * ty + 0]);
    const float rni1 = rsqrtf(nsum[i0 + 2 * ty + 1]);
    float rp0 = 0.f, rp1 = 0.f;
#pragma unroll
    for (int v = 0; v < 4; ++v) {
        const int j = j0 + 4 * tx + v;
        const bool jv = (j < C_CLS);
        const float rnj = rsqrtf(nsum[j]);
        const float d0 = acc[0][v] * rni0 * rnj;
        const float d1 = acc[1][v] * rni1 * rnj;
        const float w0 = (jv && d0 > 0.5f) ? __expf(10.f * d0) : 0.f;
        const float w1 = (jv && d1 > 0.5f) ? __expf(10.f * d1) : 0.f;
        rp0 += w0; rp1 += w1;
        *(float2*)(WT + (size_t)j * CP + i0 + 2 * ty) = make_float2(w0, w1);
    }
    sm.s.rp[2 * ty + 0][tx] = rp0;
    sm.s.rp[2 * ty + 1][tx] = rp1;
    __syncthreads();
    if (t < 64) {
        float s = 0.f;
#pragma unroll 16
        for (int k = 0; k < 16; ++k) s += sm.s.rp[t][k];
        const int i = i0 + t;
        if (i < C_CLS) atomicAdd(&rsum[i], s);
    }
}

// ---------------------------------------------------------------------------
// mmqt v2: QT[h][i] = (W @ B)^T, full-K (1024), fused nsum atomics.
// 256 blocks (8h x 32i), tile 32i x 32h, BK=128 -> 8 chunks, 512 threads.
// WT rows j>=1000 are zeros, so B pad rows contribute nothing.
// ---------------------------------------------------------------------------
__device__ __forceinline__ void mmqt_dev(BSm& sm, int b, int t,
    const float* __restrict__ WT, const float* __restrict__ B,
    float* __restrict__ QT, float* __restrict__ nsum)
{
    const int h0 = (b & 7) * 32;
    const int i0 = (b >> 3) * 32;
    const int ti = t & 31;      // i lane
    const int th = t >> 5;      // h-pair 0..15
    float acc0 = 0.f, acc1 = 0.f;
    for (int ch = 0; ch < 8; ++ch) {
        const int kb = ch * 128;
        __syncthreads();
        for (int l = t; l < 1024; l += 512) {   // W-tile (128 k x 32 i)
            const int kk = l >> 3, f = l & 7;
            *(float4*)&sm.q.Wt[kk][4 * f] =
                *(const float4*)(WT + (size_t)(kb + kk) * CP + i0 + 4 * f);
        }
        for (int l = t; l < 1024; l += 512) {   // B-tile (128 k x 32 h)
            const int kk = l >> 3, f = l & 7;
            *(float4*)&sm.q.Bt[kk][4 * f] =
                *(const float4*)(B + (size_t)(kb + kk) * HPROJ + h0 + 4 * f);
        }
        __syncthreads();
#pragma unroll 8
        for (int kk = 0; kk < 128; ++kk) {
            const float  w = sm.q.Wt[kk][ti];
            const float2 v = *(const float2*)&sm.q.Bt[kk][2 * th];
            acc0 = fmaf(w, v.x, acc0);
            acc1 = fmaf(w, v.y, acc1);
        }
    }
    const int i = i0 + ti;
    QT[(size_t)(h0 + 2 * th + 0) * CP + i] = acc0;
    QT[(size_t)(h0 + 2 * th + 1) * CP + i] = acc1;
    sm.q.nps[ti][th] = acc0 * acc0 + acc1 * acc1;
    __syncthreads();
    if (t < 32) {
        float s = 0.f;
#pragma unroll
        for (int k = 0; k < 16; ++k) s += sm.q.nps[t][k];
        atomicAdd(&nsum[i0 + t], s);
    }
}

// ---------------------------------------------------------------------------
// mm_out (full-K, 256 blocks): out[i] = (W @ V)[i] / rsum[i], V via vidx.
// grid (8c x 32i), tile 32i x 64c, K=1024 in 16 chunks, 1i x 4c per thread.
// ---------------------------------------------------------------------------
__device__ __forceinline__ void mm_out_dev(BSm& sm, int b, int t,
    const float* __restrict__ WT, const float* __restrict__ V,
    const int* __restrict__ vidx, const float* __restrict__ rsum,
    float* __restrict__ Out)
{
    const int c0 = (b & 7) * 64;
    const int i0 = (b >> 3) * 32;
    const int tx = t & 15, ty = t >> 4;   // ty 0..31 = i
    float acc[4] = {};
    for (int ch = 0; ch < 16; ++ch) {
        const int kb = ch * 64;
        __syncthreads();
        {
            const int kk = t >> 3, f = t & 7;
            *(float4*)&sm.m2.Wt[kk][4 * f] =
                *(const float4*)(WT + (size_t)(kb + kk) * CP + i0 + 4 * f);
        }
        for (int l = t; l < 1024; l += 512) {
            const int kk = l >> 4, f = l & 15;
            const int jc = min(kb + kk, C_CLS - 1);
            const int vr = vidx[jc];
            *(float4*)&sm.m2.Vt[kk][4 * f] =
                *(const float4*)(V + (size_t)vr * DIM + c0 + 4 * f);
        }
        __syncthreads();
#pragma unroll 8
        for (int kk = 0; kk < 64; ++kk) {
            const float  w = sm.m2.Wt[kk][ty];
            const float4 v = *(const float4*)&sm.m2.Vt[kk][4 * tx];
            acc[0] = fmaf(w, v.x, acc[0]);
            acc[1] = fmaf(w, v.y, acc[1]);
            acc[2] = fmaf(w, v.z, acc[2]);
            acc[3] = fmaf(w, v.w, acc[3]);
        }
    }
    const int i = i0 + ty;
    if (i < C_CLS) {
        const float s = 1.0f / rsum[i];
        float4 o = {acc[0] * s, acc[1] * s, acc[2] * s, acc[3] * s};
        *(float4*)(Out + (size_t)i * DIM + c0 + 4 * tx) = o;
    }
}

// ---------------------------------------------------------------------------
// Kernels
// ---------------------------------------------------------------------------
__global__ __launch_bounds__(512) void k_stage1(
    const float* __restrict__ attributes,
    const float* __restrict__ att_h, const float* __restrict__ att_g,
    float* __restrict__ PT, float* __restrict__ nsum1, float* __restrict__ B,
    const int* __restrict__ labels, int* __restrict__ cnt,
    int* __restrict__ perm)
{
    __shared__ BSm sm;
    const int b = blockIdx.x, t = threadIdx.x;
    if (b < 256) {
        proj1_dev(sm, b, t, attributes, att_h, PT, nsum1);
    } else if (b < 512) {
        projB_dev(sm, b - 256, t, attributes, att_g, B);
    } else {
        const int i = (b - 512) * 512 + t;
        if (i < N_IMG) {
            const int c = labels[i];
            const int p = atomicAdd(&cnt[c], 1);
            if (p < CAP) perm[c * CAP + p] = i;
        }
    }
}

__global__ __launch_bounds__(512) void k_score_gather(
    const float* __restrict__ PT, const float* __restrict__ nsum,
    float* __restrict__ WT, float* __restrict__ rsum,
    const float* __restrict__ image_feats, const int* __restrict__ cnt,
    const int* __restrict__ perm, float* __restrict__ protos, int cbase)
{
    __shared__ BSm sm;
    const int b = blockIdx.x, t = threadIdx.x;
    if (b < 256) score_dev(sm, b, t, PT, nsum, WT, rsum);
    else         gather_dev(sm, cbase + (b - 256), t, image_feats, cnt, perm, protos);
}

__global__ __launch_bounds__(512) void k_mmqt_gather(
    const float* __restrict__ WT, const float* __restrict__ B,
    float* __restrict__ QT, float* __restrict__ nsum,
    const float* __restrict__ image_feats, const int* __restrict__ cnt,
    const int* __restrict__ perm, float* __restrict__ protos, int cbase)
{
    __shared__ BSm sm;
    const int b = blockIdx.x, t = threadIdx.x;
    if (b < 256) mmqt_dev(sm, b, t, WT, B, QT, nsum);
    else         gather_dev(sm, cbase + (b - 256), t, image_feats, cnt, perm, protos);
}

__global__ __launch_bounds__(512) void k_mm_out(
    const float* __restrict__ WT, const float* __restrict__ V,
    const int* __restrict__ vidx, const float* __restrict__ rsum,
    float* __restrict__ Out)
{
    __shared__ BSm sm;
    mm_out_dev(sm, blockIdx.x, threadIdx.x, WT, V, vidx, rsum, Out);
}

// ---------------------------------------------------------------------------
extern "C" void kernel_launch(void* const* d_in, const int* in_sizes, int n_in,
                              void* d_out, int out_size, void* d_ws, size_t ws_size,
                              hipStream_t stream) {
    const float* image_feats = (const float*)d_in[0];  // [100000, 512]
    const float* attributes  = (const float*)d_in[1];  // [1000, 512]
    const float* att_g       = (const float*)d_in[2];  // [512, 256]
    const float* att_h       = (const float*)d_in[3];  // [512, 256]
    const int*   labels      = (const int*)d_in[4];    // [100000]
    const int*   tpl         = (const int*)d_in[5];    // [1000]
    float* out = (float*)d_out;                        // [1000, 512]

    float* ws     = (float*)d_ws;
    float* protos = ws;                       // 512000
    float* PT1    = protos + 512000;          // 262144  [256][1024]
    float* PT2    = PT1 + 262144;             // 262144  [256][1024]
    float* WT     = PT2 + 262144;             // 1048576 [1024][1024]
    float* B      = WT + 1048576;             // 262144  [1024][256]
    int*   cnt    = (int*)(B + 262144);       // 1024  (zero-block start)
    float* rsum1  = (float*)(cnt + 1024);     // 1024 (written, unused: scale
    float* rsum2  = rsum1 + 1024;             // 1024  cancels in stage-2 cosine)
    float* nsum1  = rsum2 + 1024;             // 1024
    float* nsum2  = nsum1 + 1024;             // 1024
    int*   perm   = (int*)(nsum2 + 1024);     // 512000

    hipMemsetAsync(cnt, 0, 5 * 1024 * sizeof(int), stream);

    // K1: proj1 (attr@att_h -> PT1, nsum1) ∥ projB (attr@att_g -> B) ∥ fill
    k_stage1<<<512 + 196, 512, 0, stream>>>(
        attributes, att_h, att_g, PT1, nsum1, B, labels, cnt, perm);
    // K2: score1 ∥ gather [0,334)
    k_score_gather<<<256 + 334, 512, 0, stream>>>(
        PT1, nsum1, WT, rsum1, image_feats, cnt, perm, protos, 0);
    // K3: mmqt v2 (W1@B -> PT2 transposed, nsum2) ∥ gather [334,667)
    k_mmqt_gather<<<256 + 333, 512, 0, stream>>>(
        WT, B, PT2, nsum2, image_feats, cnt, perm, protos, 334);
    // K4: score2 ∥ gather [667,1000)
    k_score_gather<<<256 + 333, 512, 0, stream>>>(
        PT2, nsum2, WT, rsum2, image_feats, cnt, perm, protos, 667);
    // K5: mm_out full-K, fused 1/rsum2 scale, writes out directly
    k_mm_out<<<256, 512, 0, stream>>>(WT, protos, tpl, rsum2, out);
}